// Round 1
// baseline (311.264 us; speedup 1.0000x reference)
//
#include <hip/hip_runtime.h>
#include <hip/hip_bf16.h>

#define BATCH 1024
#define FDIM  352
#define FPAD  384
#define HDIM  64

typedef short bf16x8 __attribute__((ext_vector_type(8)));
typedef float f32x4  __attribute__((ext_vector_type(4)));
typedef unsigned short ushort_t;

__device__ __forceinline__ ushort_t f2bf(float x) {
    union { float f; unsigned u; } v; v.f = x;
    unsigned u = v.u;
    unsigned r = u + 0x7FFFu + ((u >> 16) & 1u);   // RNE to bf16
    return (ushort_t)(r >> 16);
}

__device__ __forceinline__ float sigmoidf_(float x) {
    return 1.0f / (1.0f + __expf(-x));
}

// Pre-kernel: convert shared x_rep_w [352][64] fp32 -> bf16 [384][64], zero-pad rows 352..383.
__global__ void prep_kernel(const float* __restrict__ xrepw, ushort_t* __restrict__ wbf) {
    int idx = blockIdx.x * 256 + threadIdx.x;
    if (idx < FPAD * 64) {
        int f = idx >> 6;
        wbf[idx] = (f < FDIM) ? f2bf(xrepw[idx]) : (ushort_t)0;
    }
}

// One workgroup per batch row. 256 threads = 4 waves.
__global__ __launch_bounds__(256, 2) void fused_model(
    const float* __restrict__ X,    const float* __restrict__ Xsp,  const float* __restrict__ Xseq,
    const float* __restrict__ S,    const float* __restrict__ R,
    const float* __restrict__ emb,  const float* __restrict__ xrepw,
    const float* __restrict__ Qw,   const float* __restrict__ Qb,
    const float* __restrict__ Kw,   const float* __restrict__ Kb,
    const float* __restrict__ ws1,  const float* __restrict__ bs1,
    const float* __restrict__ wx2,  const float* __restrict__ bx2,
    const float* __restrict__ wsx33,const float* __restrict__ bsx33,
    const float* __restrict__ wr1,  const float* __restrict__ br1,
    const float* __restrict__ wxx2, const float* __restrict__ bxx2,
    const float* __restrict__ wrx33,const float* __restrict__ brx33,
    const float* __restrict__ fc1w, const float* __restrict__ fc1b,
    const float* __restrict__ fc2w, const float* __restrict__ fc2b,
    const float* __restrict__ fc3w, const float* __restrict__ fc3b,
    const ushort_t* __restrict__ wbf, float* __restrict__ out)
{
    // LDS: 62.2 KB total (fits static 64 KB; 2 WGs/CU on 160 KB)
    __shared__ __align__(16) ushort_t klds[FPAD * 64];     // K, bf16, XOR-swizzled rows
    __shared__ __align__(16) ushort_t scr[4][16 * 64];     // per-wave Q transpose scratch
    __shared__ float xc[FPAD];
    __shared__ float rnorm[HDIM];
    __shared__ float qbs[HDIM], kbs[HDIM];
    __shared__ float outa[FPAD];                           // X_attn_feature (352) + sx(16) + rx(16)
    __shared__ float hx[2][HDIM];
    __shared__ float a1[HDIM], a2[HDIM];

    const int b  = blockIdx.x;
    const int t  = threadIdx.x;
    const int l  = t & 63;
    const int wv = t >> 6;

    // ---------- Phase A: build Xc (padded with zeros), zero X_attn accumulator ----------
    for (int f = t; f < FPAD; f += 256) {
        float v;
        if (f < 64)       v = X[b * 64 + f];
        else if (f < 320) { int i = (f - 64) >> 3, j = (f - 64) & 7; v = Xsp[b * 32 + i] * emb[i * 8 + j]; }
        else if (f < 352) v = Xseq[b * 32 + (f - 320)];
        else              v = 0.f;
        xc[f]   = v;
        outa[f] = 0.f;
    }
    if (t < HDIM) { qbs[t] = Qb[t]; kbs[t] = Kb[t]; }
    __syncthreads();

    // ---------- Phase B: per-column norms (full fp32) ----------
    {
        const int d = t & 63, q = t >> 6;
        float acc = 0.f;
        for (int f = q; f < FDIM; f += 4) {
            float v = xc[f] * xrepw[f * 64 + d];
            acc = fmaf(v, v, acc);
        }
        float* pf = (float*)scr;   // alias scratch for partials (before transpose use)
        pf[q * 64 + d] = acc;
        __syncthreads();
        if (t < 64) {
            float n2 = pf[t] + pf[64 + t] + pf[128 + t] + pf[192 + t];
            rnorm[t] = rsqrtf(n2);
        }
        __syncthreads();
    }

    // ---------- Phase C: G1 B-operands (rnorm folded into Qw/Kw), bf16, in registers ----------
    // B-frag layout (K x N): lane holds col e = n*16+(l&15), rows d = s*32 + (l>>4)*8 + j
    bf16x8 bq[4][2], bk[4][2];
    {
        const int kg = l >> 4;
        #pragma unroll
        for (int n = 0; n < 4; ++n) {
            const int ee = n * 16 + (l & 15);
            #pragma unroll
            for (int s = 0; s < 2; ++s) {
                const int d0 = s * 32 + kg * 8;
                bf16x8 vq, vk;
                #pragma unroll
                for (int j = 0; j < 8; ++j) {
                    float rn = rnorm[d0 + j];
                    vq[j] = (short)f2bf(rn * Qw[ee * 64 + d0 + j]);
                    vk[j] = (short)f2bf(rn * Kw[ee * 64 + d0 + j]);
                }
                bq[n][s] = vq; bk[n][s] = vk;
            }
        }
    }

    // ---------- Phase G1: Q,K = diag(Xc) * (w @ {Q,K}wN) + bias; K -> LDS, Q -> A-frags ----------
    bf16x8 aq[6][2];   // Q A-fragments for this wave's 6 m-tiles (static indexing via full unroll)
    {
        const int row = l & 15;
        const int kg  = l >> 4;
        #pragma unroll
        for (int im = 0; im < 6; ++im) {
            const int f0 = (wv * 6 + im) * 16;
            bf16x8 aw[2];
            #pragma unroll
            for (int s = 0; s < 2; ++s)
                aw[s] = *reinterpret_cast<const bf16x8*>(&wbf[(f0 + row) * 64 + s * 32 + kg * 8]);

            f32x4 pq[4], pk[4];
            #pragma unroll
            for (int n = 0; n < 4; ++n) { pq[n] = (f32x4){0.f,0.f,0.f,0.f}; pk[n] = (f32x4){0.f,0.f,0.f,0.f}; }
            #pragma unroll
            for (int s = 0; s < 2; ++s) {
                #pragma unroll
                for (int n = 0; n < 4; ++n) {
                    pq[n] = __builtin_amdgcn_mfma_f32_16x16x32_bf16(aw[s], bq[n][s], pq[n], 0, 0, 0);
                    pk[n] = __builtin_amdgcn_mfma_f32_16x16x32_bf16(aw[s], bk[n][s], pk[n], 0, 0, 0);
                }
            }
            // epilogue: scale by Xc[f], add bias, convert to bf16
            // C/D layout: f = f0 + (l>>4)*4 + r, e = n*16 + (l&15)
            const int fr0 = kg * 4;
            float xcr[4];
            #pragma unroll
            for (int r = 0; r < 4; ++r) xcr[r] = xc[f0 + fr0 + r];
            #pragma unroll
            for (int n = 0; n < 4; ++n) {
                const int e = n * 16 + (l & 15);
                const float qbe = qbs[e], kbe = kbs[e];
                #pragma unroll
                for (int r = 0; r < 4; ++r) {
                    const int f  = f0 + fr0 + r;
                    const int fr = fr0 + r;
                    klds[f * 64 + (e ^ ((f & 7) << 3))]      = f2bf(fmaf(xcr[r], pk[n][r], kbe));
                    scr[wv][fr * 64 + (e ^ ((fr & 7) << 3))] = f2bf(fmaf(xcr[r], pq[n][r], qbe));
                }
            }
            // wave-local transpose readback: C/D layout -> A layout
            asm volatile("s_waitcnt lgkmcnt(0)" ::: "memory");
            __builtin_amdgcn_sched_barrier(0);
            #pragma unroll
            for (int s = 0; s < 2; ++s)
                aq[im][s] = *reinterpret_cast<const bf16x8*>(
                    &scr[wv][row * 64 + ((s * 32 + kg * 8) ^ ((row & 7) << 3))]);
            asm volatile("s_waitcnt lgkmcnt(0)" ::: "memory");   // reads done before next iter's writes
            __builtin_amdgcn_sched_barrier(0);
        }
    }
    __syncthreads();   // K fully staged

    // ---------- Phase G2: scores = Q K^T / 8, row-softmax, accumulate X_attn[g] ----------
    {
        const int row = l & 15;
        const int kg  = l >> 4;
        #pragma unroll
        for (int im = 0; im < 6; ++im) {
            const int f0 = (wv * 6 + im) * 16;
            f32x4 acc[22];
            #pragma unroll
            for (int nt = 0; nt < 22; ++nt) {     // g < 352 only: padded n-tiles skipped
                const int g = nt * 16 + row;
                bf16x8 b0 = *reinterpret_cast<const bf16x8*>(&klds[g * 64 + ((kg * 8)      ^ ((g & 7) << 3))]);
                bf16x8 b1 = *reinterpret_cast<const bf16x8*>(&klds[g * 64 + ((32 + kg * 8) ^ ((g & 7) << 3))]);
                f32x4 a = (f32x4){0.f,0.f,0.f,0.f};
                a = __builtin_amdgcn_mfma_f32_16x16x32_bf16(aq[im][0], b0, a, 0, 0, 0);
                a = __builtin_amdgcn_mfma_f32_16x16x32_bf16(aq[im][1], b1, a, 0, 0, 0);
                acc[nt] = a;
            }
            // scale + row max (rows f = f0 + kg*4 + r, spread over 16 lanes sharing kg)
            float m[4] = {-1e30f, -1e30f, -1e30f, -1e30f};
            #pragma unroll
            for (int nt = 0; nt < 22; ++nt) {
                #pragma unroll
                for (int r = 0; r < 4; ++r) {
                    float s = acc[nt][r] * 0.125f;
                    acc[nt][r] = s;
                    m[r] = fmaxf(m[r], s);
                }
            }
            #pragma unroll
            for (int r = 0; r < 4; ++r) {
                #pragma unroll
                for (int off = 1; off < 16; off <<= 1)
                    m[r] = fmaxf(m[r], __shfl_xor(m[r], off, 64));
            }
            float lsum[4] = {0.f, 0.f, 0.f, 0.f};
            #pragma unroll
            for (int nt = 0; nt < 22; ++nt) {
                #pragma unroll
                for (int r = 0; r < 4; ++r) {
                    float p = __expf(acc[nt][r] - m[r]);
                    acc[nt][r] = p;
                    lsum[r] += p;
                }
            }
            #pragma unroll
            for (int r = 0; r < 4; ++r) {
                #pragma unroll
                for (int off = 1; off < 16; off <<= 1)
                    lsum[r] += __shfl_xor(lsum[r], off, 64);
            }
            float coef[4];
            #pragma unroll
            for (int r = 0; r < 4; ++r) coef[r] = xc[f0 + kg * 4 + r] / lsum[r];  // Xc=0 for padded f
            #pragma unroll
            for (int nt = 0; nt < 22; ++nt) {
                float po = coef[0]*acc[nt][0] + coef[1]*acc[nt][1] + coef[2]*acc[nt][2] + coef[3]*acc[nt][3];
                po += __shfl_xor(po, 16, 64);
                po += __shfl_xor(po, 32, 64);
                if (l < 16) atomicAdd(&outa[nt * 16 + l], po);
            }
        }
    }
    __syncthreads();

    // ---------- Phase H: h_x = sigmoid(Xc @ w2^T + b2) for both branches ----------
    if (wv < 2) {
        const float* w2 = (wv == 0) ? wx2 : wxx2;
        const float* b2 = (wv == 0) ? bx2 : bxx2;
        const int fo = l & 3;
        const int hb = l >> 2;            // 0..15
        float acc[4] = {0.f, 0.f, 0.f, 0.f};
        for (int f = fo; f < FDIM; f += 4) {
            float xv = xc[f];
            #pragma unroll
            for (int c = 0; c < 4; ++c)
                acc[c] = fmaf(xv, w2[(hb + 16 * c) * FDIM + f], acc[c]);
        }
        #pragma unroll
        for (int c = 0; c < 4; ++c) {
            acc[c] += __shfl_xor(acc[c], 1, 64);
            acc[c] += __shfl_xor(acc[c], 2, 64);
        }
        if (fo == 0) {
            #pragma unroll
            for (int c = 0; c < 4; ++c) {
                int h = hb + 16 * c;
                hx[wv][h] = sigmoidf_(acc[c] + b2[h]);
            }
        }
    }
    __syncthreads();

    // ---------- Phase I: interaction attention (wave0 = S branch, wave1 = R branch) ----------
    if (wv < 2) {
        const float* sv  = (wv == 0) ? S     : R;
        const float* w1  = (wv == 0) ? ws1   : wr1;
        const float* b1  = (wv == 0) ? bs1   : br1;
        const float* w33 = (wv == 0) ? wsx33 : wrx33;
        const float  b33 = (wv == 0) ? bsx33[0] : brx33[0];
        const float w1h = w1[l], b1h = b1[l], w33h = w33[l], hxh = hx[wv][l];
        float myscore = 0.f;
        for (int i = 0; i < 16; ++i) {
            float s  = sv[b * 16 + i];
            float hs = sigmoidf_(fmaf(s, w1h, b1h));
            float v  = fmaxf(hs + hxh, 0.f) * w33h;
            #pragma unroll
            for (int off = 1; off < 64; off <<= 1) v += __shfl_xor(v, off, 64);
            if (i == l) myscore = v + b33;          // lane i keeps score_i (i < 16)
        }
        float mm = myscore;
        #pragma unroll
        for (int off = 1; off < 16; off <<= 1) mm = fmaxf(mm, __shfl_xor(mm, off, 64));
        float p  = __expf(myscore - mm);
        float ss = p;
        #pragma unroll
        for (int off = 1; off < 16; off <<= 1) ss += __shfl_xor(ss, off, 64);
        if (l < 16) outa[FDIM + wv * 16 + l] = sv[b * 16 + l] * (p / ss);
    }
    __syncthreads();

    // ---------- Phase J: MLP head ----------
    {   // fc1: [64 x 384] — h = t>>2, 4 lanes per h over j
        const int h = t >> 2, jo = t & 3;
        float acc = 0.f;
        for (int j = jo; j < 384; j += 4)
            acc = fmaf(outa[j], fc1w[h * 384 + j], acc);
        acc += __shfl_xor(acc, 1, 64);
        acc += __shfl_xor(acc, 2, 64);
        if (jo == 0) a1[h] = fmaxf(acc + fc1b[h], 0.f);
    }
    __syncthreads();
    {   // fc2: [64 x 64]
        const int h = t >> 2, jo = t & 3;
        float acc = 0.f;
        #pragma unroll
        for (int j = jo; j < 64; j += 4)
            acc = fmaf(a1[j], fc2w[h * 64 + j], acc);
        acc += __shfl_xor(acc, 1, 64);
        acc += __shfl_xor(acc, 2, 64);
        if (jo == 0) a2[h] = fmaxf(acc + fc2b[h], 0.f);
    }
    __syncthreads();
    if (wv == 0) {   // fc3: [1 x 64]
        float v = fc3w[l] * a2[l];
        #pragma unroll
        for (int off = 1; off < 64; off <<= 1) v += __shfl_xor(v, off, 64);
        if (l == 0) out[b] = v + fc3b[0];
    }
}

extern "C" void kernel_launch(void* const* d_in, const int* in_sizes, int n_in,
                              void* d_out, int out_size, void* d_ws, size_t ws_size,
                              hipStream_t stream) {
    const float* X     = (const float*)d_in[0];
    const float* Xsp   = (const float*)d_in[1];
    const float* Xseq  = (const float*)d_in[2];
    const float* S     = (const float*)d_in[3];
    const float* R     = (const float*)d_in[4];
    const float* emb   = (const float*)d_in[5];
    const float* xrepw = (const float*)d_in[6];
    const float* Qw    = (const float*)d_in[7];
    const float* Qb    = (const float*)d_in[8];
    const float* Kw    = (const float*)d_in[9];
    const float* Kb    = (const float*)d_in[10];
    // d_in[11], d_in[12] = Vw, Vb : dead code in reference (attn@V unused)
    const float* ws1   = (const float*)d_in[13];
    const float* bs1   = (const float*)d_in[14];
    const float* wx2   = (const float*)d_in[15];
    const float* bx2   = (const float*)d_in[16];
    const float* wsx33 = (const float*)d_in[17];
    const float* bsx33 = (const float*)d_in[18];
    const float* wr1   = (const float*)d_in[19];
    const float* br1   = (const float*)d_in[20];
    const float* wxx2  = (const float*)d_in[21];
    const float* bxx2  = (const float*)d_in[22];
    const float* wrx33 = (const float*)d_in[23];
    const float* brx33 = (const float*)d_in[24];
    const float* fc1w  = (const float*)d_in[25];
    const float* fc1b  = (const float*)d_in[26];
    const float* fc2w  = (const float*)d_in[27];
    const float* fc2b  = (const float*)d_in[28];
    const float* fc3w  = (const float*)d_in[29];
    const float* fc3b  = (const float*)d_in[30];

    ushort_t* wbf = (ushort_t*)d_ws;   // 384*64*2 = 49152 B

    prep_kernel<<<(FPAD * 64 + 255) / 256, 256, 0, stream>>>(xrepw, wbf);
    fused_model<<<BATCH, 256, 0, stream>>>(
        X, Xsp, Xseq, S, R, emb, xrepw,
        Qw, Qb, Kw, Kb,
        ws1, bs1, wx2, bx2, wsx33, bsx33,
        wr1, br1, wxx2, bxx2, wrx33, brx33,
        fc1w, fc1b, fc2w, fc2b, fc3w, fc3b,
        wbf, (float*)d_out);
}